// Round 5
// baseline (532.895 us; speedup 1.0000x reference)
//
#include <hip/hip_runtime.h>

typedef _Float16 h16;
typedef _Float16 h4 __attribute__((ext_vector_type(4)));
typedef _Float16 h8 __attribute__((ext_vector_type(8)));
typedef float f4 __attribute__((ext_vector_type(4)));

#define NB 8192
#define NENC 4096
#define NH 128
#define NL 10
#define NT 12
#define PAD 136
#define L2E 1.4426950408889634f
#define K2 -2.8853900817779268f

// ---- workspace layout (element offsets in halfs unless noted) ----
#define OFF_FCIN 0                    // packed fc_in_W  [128 x 4096] fp16
#define SZ_FCIN (128*4096)
#define OFF_W (OFF_FCIN + SZ_FCIN)    // packed Wih/Whh  [10][2][512 x 128] fp16, PRE-SCALED
#define SZ_W (10*2*512*128)
#define OFF_FCOUT (OFF_W + SZ_W)      // packed fc_out_W [80 x 128] fp16
#define SZ_FCOUT (80*128)
#define OFF_ENC (OFF_FCOUT + SZ_FCOUT) // enc (relu(fc_in)) [8192 x 128] fp16
#define SZ_ENC (8192*128)
#define OFF_GX0 (OFF_ENC + SZ_ENC)    // GX0 = enc@Wih0^T + b0 (scaled), lane-layout fp16
#define SZ_GX0 (8192*512)
#define BYTE_BIAS ((OFF_GX0 + SZ_GX0)*2) // combined bias [10][512] f32, PRE-SCALED (byte offset)

__device__ __forceinline__ f4 splat4(float v) { f4 r; r[0]=v; r[1]=v; r[2]=v; r[3]=v; return r; }
__device__ __forceinline__ h8 cvt8(float4 a, float4 b) {
  h8 r; r[0]=(h16)a.x; r[1]=(h16)a.y; r[2]=(h16)a.z; r[3]=(h16)a.w;
  r[4]=(h16)b.x; r[5]=(h16)b.y; r[6]=(h16)b.z; r[7]=(h16)b.w; return r;
}
__device__ __forceinline__ h8 cvt8s(float4 a, float4 b, float sc) {
  h8 r; r[0]=(h16)(a.x*sc); r[1]=(h16)(a.y*sc); r[2]=(h16)(a.z*sc); r[3]=(h16)(a.w*sc);
  r[4]=(h16)(b.x*sc); r[5]=(h16)(b.y*sc); r[6]=(h16)(b.z*sc); r[7]=(h16)(b.w*sc); return r;
}

// Fused LSTM cell with PRE-SCALED gate pre-activations (see round-2 notes).
// 5 exp2 + 2 rcp + 1 const-mul per element.
__device__ __forceinline__ h16 cell(float iv, float fv, float gv, float ov, float& c) {
  float ei = __builtin_amdgcn_exp2f(iv);
  float ef = __builtin_amdgcn_exp2f(fv);
  float eg = __builtin_amdgcn_exp2f(gv);
  float eo = __builtin_amdgcn_exp2f(ov);
  float ai = 1.f + ei, af = 1.f + ef, ag = 1.f + eg;
  float m1 = ai * ag;
  float R1 = __builtin_amdgcn_rcpf(af * m1);
  float cc = R1 * fmaf(af, 1.f - eg, c * m1);
  c = cc;
  float ec = __builtin_amdgcn_exp2f(K2 * cc);
  float R2 = __builtin_amdgcn_rcpf((1.f + eo) * (1.f + ec));
  return (h16)(R2 * (1.f - ec));
}

// ---------------- prep: convert + pack weights (8 elems/thread) ----------------
__global__ __launch_bounds__(256) void prep(const float* __restrict__ fcinW,
                                            const float* __restrict__ Wih,
                                            const float* __restrict__ Whh,
                                            const float* __restrict__ bih,
                                            const float* __restrict__ bhh,
                                            const float* __restrict__ fcoutW,
                                            h16* __restrict__ wsh,
                                            float* __restrict__ wbias) {
  int idx = blockIdx.x * 256 + threadIdx.x;
  if (idx < 65536) {                          // fc_in_W [128][4096], Kd8=512
    int r = idx >> 9, k8 = idx & 511;
    const float* src = fcinW + r * 4096 + k8 * 8;
    h8 v = cvt8(*(const float4*)src, *(const float4*)(src + 4));
    *(h8*)(wsh + OFF_FCIN + (((r >> 4) * 512 + k8) * 128 + (r & 15) * 8)) = v;
  } else if (idx < 229376) {                  // Wih/Whh [10][512][128], Kd8=16, pre-scaled
    int rel = idx - 65536;
    int l = rel >> 14, rr = rel & 16383;
    int ssel = rr >> 13, rk8 = rr & 8191;
    int r = rk8 >> 4, k8 = rk8 & 15;
    float sc = ((r >> 7) == 2) ? (-2.f * L2E) : (-L2E);
    const float* src = (ssel ? Whh : Wih) + l * 65536 + r * 128 + k8 * 8;
    h8 v = cvt8s(*(const float4*)src, *(const float4*)(src + 4), sc);
    *(h8*)(wsh + OFF_W + (l * 2 + ssel) * 65536 +
           (((r >> 4) * 16 + k8) * 128 + (r & 15) * 8)) = v;
  } else if (idx < 230656) {                  // fc_out_W padded to [80][128]
    int rel = idx - 229376;
    int r = rel >> 4, k8 = rel & 15;
    h8 v;
    if (r < 75) {
      const float* src = fcoutW + r * 128 + k8 * 8;
      v = cvt8(*(const float4*)src, *(const float4*)(src + 4));
    } else {
      for (int j = 0; j < 8; ++j) v[j] = (h16)0.f;
    }
    *(h8*)(wsh + OFF_FCOUT + (((r >> 4) * 16 + k8) * 128 + (r & 15) * 8)) = v;
  } else if (idx < 235776) {
    int rel = idx - 230656;
    int col = rel & 511;
    float sc = ((col >> 7) == 2) ? (-2.f * L2E) : (-L2E);
    wbias[rel] = (bih[rel] + bhh[rel]) * sc;
  }
}

// ---------------- fc_in GEMM: enc = relu(A @ W^T + b), fp16 out ----------------
// K-split: each of the 4 waves handles a 1024-wide K-chunk of the SAME 16 rows
// (A read exactly once per block), covering all 128 output cols (8 col-tiles).
// Partial sums reduced through LDS; bias+ReLU fused in the reduction.
__global__ __launch_bounds__(256) void kin(const float* __restrict__ A,
                                           const float* __restrict__ bvec,
                                           h16* __restrict__ wsh) {
  __shared__ float red[4][16][129];   // 33 KB
  const h16* Wp = wsh + OFF_FCIN;
  h16* ench = wsh + OFF_ENC;
  int tid = threadIdx.x;
  int w = tid >> 6, lane = tid & 63, s = lane & 15, q = lane >> 4;
  int m0 = blockIdx.x * 16;
  f4 acc[8];
#pragma unroll
  for (int ct = 0; ct < 8; ++ct) acc[ct] = splat4(0.f);
  const float* arow = A + (size_t)(m0 + s) * NENC + w * 1024;
  // packed W index: (r>>4)*512*128 + k8*128 + (r&15)*8 ; r = out col, k8 = k/8
  const h16* wpk = Wp + ((size_t)(w * 128 + q)) * 128 + s * 8;
#pragma unroll 4
  for (int kb = 0; kb < 32; ++kb) {
    int k0 = kb * 32 + q * 8;
    float4 x0 = *(const float4*)(arow + k0);
    float4 x1 = *(const float4*)(arow + k0 + 4);
    h8 af = cvt8(x0, x1);
#pragma unroll
    for (int ct = 0; ct < 8; ++ct) {
      h8 b = *(const h8*)(wpk + ((size_t)ct * 512 + kb * 4) * 128);
      acc[ct] = __builtin_amdgcn_mfma_f32_16x16x32_f16(af, b, acc[ct], 0, 0, 0);
    }
  }
#pragma unroll
  for (int ct = 0; ct < 8; ++ct)
#pragma unroll
    for (int r = 0; r < 4; ++r)
      red[w][q * 4 + r][ct * 16 + s] = acc[ct][r];
  __syncthreads();
#pragma unroll
  for (int i = 0; i < 8; ++i) {
    int idx = tid + i * 256;
    int row = idx >> 7, col = idx & 127;
    float v = red[0][row][col] + red[1][row][col] + red[2][row][col] + red[3][row][col]
            + bvec[col];
    v = v > 0.f ? v : 0.f;
    ench[(size_t)(m0 + row) * NH + col] = (h16)v;
  }
}

// ---------------- kin2: GX0 = enc @ Wih0^T + b0 (t-invariant layer-0 x-GEMM) ----
__global__ __launch_bounds__(256) void kin2(h16* __restrict__ wsh,
                                            const float* __restrict__ wbias) {
  int tid = threadIdx.x;
  int w2 = tid >> 6, lane = tid & 63, s = lane & 15, q = lane >> 4;
  int bid = blockIdx.x;
  int lb = bid >> 3, mt = (bid >> 2) & 1, cg = bid & 3;
  const h16* ench = wsh + OFF_ENC;
  const h16* wih0 = wsh + OFF_W;
  h16* gx0 = wsh + OFF_GX0;
  const h16* arow = ench + (size_t)(lb * 32 + mt * 16 + s) * NH;
  h8 ax[4];
#pragma unroll
  for (int kt = 0; kt < 4; ++kt) ax[kt] = *(const h8*)(arow + kt * 32 + q * 8);
#pragma unroll
  for (int ti = 0; ti < 2; ++ti) {
    int W = w2 * 2 + ti;
    int rb = cg * 8 + W;
    f4 acc = splat4(wbias[cg * 128 + W * 16 + s]);
#pragma unroll
    for (int kt = 0; kt < 4; ++kt) {
      h8 b = *(const h8*)(wih0 + (rb * 16 + kt * 4 + q) * 128 + s * 8);
      acc = __builtin_amdgcn_mfma_f32_16x16x32_f16(ax[kt], b, acc, 0, 0, 0);
    }
    h4 st; st[0] = (h16)acc[0]; st[1] = (h16)acc[1]; st[2] = (h16)acc[2]; st[3] = (h16)acc[3];
    *(h4*)(gx0 + ((((size_t)lb * 8 + W) * 8 + cg * 2 + mt) * 64 + lane) * 4) = st;
  }
}

// ---------------- persistent LSTM + output head ----------------
// grid 256 = 1 WG/CU, block 512 = 8 waves (2/SIMD), 32 batch rows/WG.
// Ring [row][slot][col]: immediate-offset DS addressing (round 2).
// Round 3: cross-iteration x-prefetch. x(t+1)'s slot (rw+2 at issue time) is
// stable across the barrier, so its 8 ds_read_b128 are issued at the END of
// iteration t-1 (draining under the barrier + next h-GEMM), and the x-GEMM
// consumes registers only. Post-barrier LDS storm halves (only h-reads remain).
// h-writes moved before the x-GEMM so they drain under MFMA issue.
// Schedule per (l,t):
//   barrier -> h-reads+hGEMM(t) -> cell+write h(t) -> xGEMM(t+1) from regs
//           -> issue prefetch x(t+2) -> barrier
__global__ __launch_bounds__(512, 2) void lstm(h16* __restrict__ wsh,
                                               const float* __restrict__ wbias,
                                               const float* __restrict__ fcoutb,
                                               float* __restrict__ out) {
  __shared__ h16 ring[32][13][PAD];   // 113152 B
  __shared__ float probst[32 * 26];
  int tid = threadIdx.x;
  int w = tid >> 6, lane = tid & 63, s = lane & 15, q = lane >> 4;
  int brow = blockIdx.x * 32;
  h8 wx[4][4], wh[4][4];
  f4 bbv[4];
  float c[2][4];
  h16* rd0 = &ring[s][0][q * 8];
  h16* rd1 = &ring[16 + s][0][q * 8];
  h16* wr0 = &ring[q * 4][0][w * 16 + s];
  h16* wr1 = &ring[16 + q * 4][0][w * 16 + s];
#define RSTRIDE (13 * PAD)   // row stride in halfs (3536 B)

  // ---------- layer 0: acc chains from register-resident GX0 ----------
  {
    const h16* whh = wsh + OFF_W + 65536;
#pragma unroll
    for (int g = 0; g < 4; ++g)
#pragma unroll
      for (int kt = 0; kt < 4; ++kt)
        wh[g][kt] = *(const h8*)(whh + (((g * 8 + w) * 16 + kt * 4 + q) * 128) + s * 8);
    f4 gx[4][2];
    const h16* gxp = wsh + OFF_GX0 + ((size_t)blockIdx.x * 8 + w) * 8 * 256 + (size_t)lane * 4;
#pragma unroll
    for (int g = 0; g < 4; ++g)
#pragma unroll
      for (int mt = 0; mt < 2; ++mt) {
        h4 v = *(const h4*)(gxp + (g * 2 + mt) * 256);
        f4 a; a[0] = (float)v[0]; a[1] = (float)v[1]; a[2] = (float)v[2]; a[3] = (float)v[3];
        gx[g][mt] = a;
      }
#pragma unroll
    for (int mt = 0; mt < 2; ++mt)
#pragma unroll
      for (int r = 0; r < 4; ++r) c[mt][r] = 0.f;
    // t = 0: cell directly on gx, write to slot 11
    {
      h16* q0 = wr0 + 11 * PAD;
      h16* q1 = wr1 + 11 * PAD;
#pragma unroll
      for (int mt = 0; mt < 2; ++mt) {
        h16* qq = mt ? q1 : q0;
#pragma unroll
        for (int r = 0; r < 4; ++r)
          qq[r * RSTRIDE] = cell(gx[0][mt][r], gx[1][mt][r], gx[2][mt][r], gx[3][mt][r], c[mt][r]);
      }
    }
    int rw = 12;
    for (int t = 1; t < NT; ++t) {
      __syncthreads();
      int rh = rw - 1; if (rh < 0) rh += 13;
      f4 acc[4][2];
      const h16* p0 = rd0 + rh * PAD;
      const h16* p1 = rd1 + rh * PAD;
#pragma unroll
      for (int mt = 0; mt < 2; ++mt) {
        const h16* pp = mt ? p1 : p0;
        h8 ah[4];
#pragma unroll
        for (int kt = 0; kt < 4; ++kt) ah[kt] = *(const h8*)(pp + kt * 32);
#pragma unroll
        for (int g = 0; g < 4; ++g) {
          acc[g][mt] = __builtin_amdgcn_mfma_f32_16x16x32_f16(ah[0], wh[g][0], gx[g][mt], 0, 0, 0);
#pragma unroll
          for (int kt = 1; kt < 4; ++kt)
            acc[g][mt] = __builtin_amdgcn_mfma_f32_16x16x32_f16(ah[kt], wh[g][kt], acc[g][mt], 0, 0, 0);
        }
      }
      h16* q0 = wr0 + rw * PAD;
      h16* q1 = wr1 + rw * PAD;
#pragma unroll
      for (int mt = 0; mt < 2; ++mt) {
        h16* qq = mt ? q1 : q0;
#pragma unroll
        for (int r = 0; r < 4; ++r)
          qq[r * RSTRIDE] = cell(acc[0][mt][r], acc[1][mt][r], acc[2][mt][r], acc[3][mt][r], c[mt][r]);
      }
      ++rw; if (rw >= 13) rw = 0;
    }
  }
  // ---------- layers 1..9 (register-fed x-GEMM via cross-iter prefetch) ----------
  for (int l = 1; l < NL; ++l) {
    const h16* wih = wsh + OFF_W + (size_t)(l * 2) * 65536;
    const h16* whh = wih + 65536;
#pragma unroll
    for (int g = 0; g < 4; ++g) {
#pragma unroll
      for (int kt = 0; kt < 4; ++kt) {
        int off = (((g * 8 + w) * 16 + kt * 4 + q) * 128) + s * 8;
        wx[g][kt] = *(const h8*)(wih + off);
        wh[g][kt] = *(const h8*)(whh + off);
      }
      bbv[g] = splat4(wbias[l * 512 + g * 128 + w * 16 + s]);
    }
#pragma unroll
    for (int mt = 0; mt < 2; ++mt)
#pragma unroll
      for (int r = 0; r < 4; ++r) c[mt][r] = 0.f;
    int rw = 11 - l;                 // rw(t=0) in [2,10]
    f4 acc[4][2];
    h8 ax[2][4];                     // prefetched x fragments (both mt)
    // prologue: x(0) -> xGEMM(0); prefetch x(1). Slots rw+1, rw+2 (<13, no wrap).
    {
      const h16* p0 = rd0 + (rw + 1) * PAD;
      const h16* p1 = rd1 + (rw + 1) * PAD;
#pragma unroll
      for (int mt = 0; mt < 2; ++mt) {
        const h16* pp = mt ? p1 : p0;
#pragma unroll
        for (int kt = 0; kt < 4; ++kt) ax[mt][kt] = *(const h8*)(pp + kt * 32);
      }
#pragma unroll
      for (int mt = 0; mt < 2; ++mt)
#pragma unroll
        for (int g = 0; g < 4; ++g) {
          acc[g][mt] = __builtin_amdgcn_mfma_f32_16x16x32_f16(ax[mt][0], wx[g][0], bbv[g], 0, 0, 0);
#pragma unroll
          for (int kt = 1; kt < 4; ++kt)
            acc[g][mt] = __builtin_amdgcn_mfma_f32_16x16x32_f16(ax[mt][kt], wx[g][kt], acc[g][mt], 0, 0, 0);
        }
      const h16* n0 = rd0 + (rw + 2) * PAD;
      const h16* n1 = rd1 + (rw + 2) * PAD;
#pragma unroll
      for (int mt = 0; mt < 2; ++mt) {
        const h16* pp = mt ? n1 : n0;
#pragma unroll
        for (int kt = 0; kt < 4; ++kt) ax[mt][kt] = *(const h8*)(pp + kt * 32);
      }
    }
    for (int t = 0; t < NT; ++t) {
      __syncthreads();
      if (t > 0) {                   // h-GEMM chains into acc (holds bias + x(t))
        int rh = rw - 1; if (rh < 0) rh += 13;
        const h16* p0 = rd0 + rh * PAD;
        const h16* p1 = rd1 + rh * PAD;
#pragma unroll
        for (int mt = 0; mt < 2; ++mt) {
          const h16* pp = mt ? p1 : p0;
          h8 ah[4];
#pragma unroll
          for (int kt = 0; kt < 4; ++kt) ah[kt] = *(const h8*)(pp + kt * 32);
#pragma unroll
          for (int g = 0; g < 4; ++g)
#pragma unroll
            for (int kt = 0; kt < 4; ++kt)
              acc[g][mt] = __builtin_amdgcn_mfma_f32_16x16x32_f16(ah[kt], wh[g][kt], acc[g][mt], 0, 0, 0);
        }
      }
      // cell(t) + immediate h-write (drains under the following MFMA issue)
      h16* q0 = wr0 + rw * PAD;
      h16* q1 = wr1 + rw * PAD;
#pragma unroll
      for (int mt = 0; mt < 2; ++mt) {
        h16* qq = mt ? q1 : q0;
#pragma unroll
        for (int r = 0; r < 4; ++r)
          qq[r * RSTRIDE] = cell(acc[0][mt][r], acc[1][mt][r], acc[2][mt][r], acc[3][mt][r], c[mt][r]);
      }
      if (t < 11) {                  // xGEMM(t+1) from prefetched regs, C = bias
#pragma unroll
        for (int mt = 0; mt < 2; ++mt)
#pragma unroll
          for (int g = 0; g < 4; ++g) {
            acc[g][mt] = __builtin_amdgcn_mfma_f32_16x16x32_f16(ax[mt][0], wx[g][0], bbv[g], 0, 0, 0);
#pragma unroll
            for (int kt = 1; kt < 4; ++kt)
              acc[g][mt] = __builtin_amdgcn_mfma_f32_16x16x32_f16(ax[mt][kt], wx[g][kt], acc[g][mt], 0, 0, 0);
          }
        if (t < 10) {                // prefetch x(t+2) from slot rw+3 (stable)
          int rx = rw + 3; if (rx >= 13) rx -= 13;
          const h16* n0 = rd0 + rx * PAD;
          const h16* n1 = rd1 + rx * PAD;
#pragma unroll
          for (int mt = 0; mt < 2; ++mt) {
            const h16* pp = mt ? n1 : n0;
#pragma unroll
            for (int kt = 0; kt < 4; ++kt) ax[mt][kt] = *(const h8*)(pp + kt * 32);
          }
        }
      }
      ++rw; if (rw >= 13) rw = 0;
    }
  }
  // ---- output head: layer-9 h(t) lives in ring slot (t+2)%13 ----
  __syncthreads();
  h8 wo[5][4];
  float bo[5];
  const h16* fco = wsh + OFF_FCOUT;
#pragma unroll
  for (int nt = 0; nt < 5; ++nt) {
#pragma unroll
    for (int kt = 0; kt < 4; ++kt)
      wo[nt][kt] = *(const h8*)(fco + (nt * 16 + kt * 4 + q) * 128 + s * 8);
    int col = nt * 16 + s;
    bo[nt] = (col < 75) ? fcoutb[col] : 0.f;
  }
  int tcount = (w < 4) ? 2 : 1;
  for (int ti = 0; ti < tcount; ++ti) {
    int t = w + ti * 8;
    int sl = t + 2; if (sl >= 13) sl -= 13;
#pragma unroll
    for (int mt = 0; mt < 2; ++mt) {
      const h16* pp = (mt ? rd1 : rd0) + sl * PAD;
      h8 ax[4];
#pragma unroll
      for (int kt = 0; kt < 4; ++kt) ax[kt] = *(const h8*)(pp + kt * 32);
#pragma unroll
      for (int nt = 0; nt < 5; ++nt) {
        f4 a = splat4(bo[nt]);
#pragma unroll
        for (int kt = 0; kt < 4; ++kt)
          a = __builtin_amdgcn_mfma_f32_16x16x32_f16(ax[kt], wo[nt][kt], a, 0, 0, 0);
        int col = nt * 16 + s;
#pragma unroll
        for (int r = 0; r < 4; ++r) {
          int row = mt * 16 + q * 4 + r;
          int b = brow + row;
          float v = a[r];
          if (col < 50)
            out[(size_t)b * 600 + (col >> 1) * 24 + t * 2 + (col & 1)] = v;
          if (t == 11 && col >= 50 && col < 75)
            probst[row * 26 + (col - 50)] = v;
        }
      }
    }
  }
  __syncthreads();
  if (tid < 32) {
    float vals[25];
    float m = -1e30f;
#pragma unroll
    for (int j = 0; j < 25; ++j) { vals[j] = probst[tid * 26 + j]; m = vals[j] > m ? vals[j] : m; }
    float sum = 0.f;
#pragma unroll
    for (int j = 0; j < 25; ++j) {
      float e = __builtin_amdgcn_exp2f((vals[j] - m) * L2E);
      vals[j] = e; sum += e;
    }
    float rs = 1.0f / sum;
    size_t pb = (size_t)4915200 + (size_t)(brow + tid) * 25;
#pragma unroll
    for (int j = 0; j < 25; ++j) out[pb + j] = vals[j] * rs;
  }
}

extern "C" void kernel_launch(void* const* d_in, const int* in_sizes, int n_in,
                              void* d_out, int out_size, void* d_ws, size_t ws_size,
                              hipStream_t stream) {
  const float* backbone = (const float*)d_in[0];
  const float* fcinW    = (const float*)d_in[1];
  const float* fcinb    = (const float*)d_in[2];
  const float* Wih      = (const float*)d_in[3];
  const float* Whh      = (const float*)d_in[4];
  const float* bih      = (const float*)d_in[5];
  const float* bhh      = (const float*)d_in[6];
  const float* fcoutW   = (const float*)d_in[7];
  const float* fcoutb   = (const float*)d_in[8];
  h16* wsh = (h16*)d_ws;
  float* wbias = (float*)((char*)d_ws + BYTE_BIAS);

  prep<<<922, 256, 0, stream>>>(fcinW, Wih, Whh, bih, bhh, fcoutW, wsh, wbias);
  kin<<<512, 256, 0, stream>>>(backbone, fcinb, wsh);
  kin2<<<2048, 256, 0, stream>>>(wsh, wbias);
  lstm<<<256, 512, 0, stream>>>(wsh, wbias, fcoutb, (float*)d_out);
}

// Round 6
// 509.268 us; speedup vs baseline: 1.0464x; 1.0464x over previous
//
#include <hip/hip_runtime.h>

typedef _Float16 h16;
typedef _Float16 h4 __attribute__((ext_vector_type(4)));
typedef _Float16 h8 __attribute__((ext_vector_type(8)));
typedef float f4 __attribute__((ext_vector_type(4)));

#define NB 8192
#define NENC 4096
#define NH 128
#define NL 10
#define NT 12
#define PAD 136
#define L2E 1.4426950408889634f
#define K2 -2.8853900817779268f

// ---- workspace layout (element offsets in halfs unless noted) ----
#define OFF_FCIN 0                    // packed fc_in_W  [128 x 4096] fp16
#define SZ_FCIN (128*4096)
#define OFF_W (OFF_FCIN + SZ_FCIN)    // packed Wih/Whh  [10][2][512 x 128] fp16, PRE-SCALED
#define SZ_W (10*2*512*128)
#define OFF_FCOUT (OFF_W + SZ_W)      // packed fc_out_W [80 x 128] fp16
#define SZ_FCOUT (80*128)
#define OFF_ENC (OFF_FCOUT + SZ_FCOUT) // enc (relu(fc_in)) [8192 x 128] fp16
#define SZ_ENC (8192*128)
#define OFF_GX0 (OFF_ENC + SZ_ENC)    // GX0 = enc@Wih0^T + b0 (scaled), lane-layout fp16
#define SZ_GX0 (8192*512)
#define BYTE_BIAS ((OFF_GX0 + SZ_GX0)*2) // combined bias [10][512] f32, PRE-SCALED (byte offset)

__device__ __forceinline__ f4 splat4(float v) { f4 r; r[0]=v; r[1]=v; r[2]=v; r[3]=v; return r; }
__device__ __forceinline__ h8 cvt8(float4 a, float4 b) {
  h8 r; r[0]=(h16)a.x; r[1]=(h16)a.y; r[2]=(h16)a.z; r[3]=(h16)a.w;
  r[4]=(h16)b.x; r[5]=(h16)b.y; r[6]=(h16)b.z; r[7]=(h16)b.w; return r;
}
__device__ __forceinline__ h8 cvt8s(float4 a, float4 b, float sc) {
  h8 r; r[0]=(h16)(a.x*sc); r[1]=(h16)(a.y*sc); r[2]=(h16)(a.z*sc); r[3]=(h16)(a.w*sc);
  r[4]=(h16)(b.x*sc); r[5]=(h16)(b.y*sc); r[6]=(h16)(b.z*sc); r[7]=(h16)(b.w*sc); return r;
}

__device__ __forceinline__ f4 exp2v(f4 x) {
  f4 r; r[0]=__builtin_amdgcn_exp2f(x[0]); r[1]=__builtin_amdgcn_exp2f(x[1]);
  r[2]=__builtin_amdgcn_exp2f(x[2]); r[3]=__builtin_amdgcn_exp2f(x[3]); return r;
}
__device__ __forceinline__ f4 rcpv(f4 x) {
  f4 r; r[0]=__builtin_amdgcn_rcpf(x[0]); r[1]=__builtin_amdgcn_rcpf(x[1]);
  r[2]=__builtin_amdgcn_rcpf(x[2]); r[3]=__builtin_amdgcn_rcpf(x[3]); return r;
}

// Fused LSTM cell, 4 elements at once. Gate pre-activations arrive PRE-SCALED
// (iv=-log2e*i, fv=-log2e*f, gv=-2log2e*g, ov=-log2e*o). Exact algebra:
//   c' = (c*ai*ag + af*(1-eg)) / (af*ai*ag);  h = (1-ec)/(ao*ac)
// Trans ops stay per-lane scalar (5 exp2 + 2 rcp per elem); all muls/adds are
// f4 vector ops so clang can emit v_pk_{add,mul,fma}_f32 (halves cell VALU).
__device__ __forceinline__ h4 cell4(f4 iv, f4 fv, f4 gv, f4 ov, f4& c) {
  f4 ei = exp2v(iv), ef = exp2v(fv), eg = exp2v(gv), eo = exp2v(ov);
  f4 one = splat4(1.f);
  f4 ai = one + ei, af = one + ef, ag = one + eg, ao = one + eo;
  f4 m1 = ai * ag;
  f4 R1 = rcpv(af * m1);
  f4 cc = R1 * (af * (one - eg) + c * m1);
  c = cc;
  f4 ec = exp2v(splat4(K2) * cc);
  f4 R2 = rcpv(ao * (one + ec));
  f4 hv = R2 * (one - ec);
  h4 o; o[0]=(h16)hv[0]; o[1]=(h16)hv[1]; o[2]=(h16)hv[2]; o[3]=(h16)hv[3];
  return o;
}

// ---------------- prep: convert + pack weights (8 elems/thread) ----------------
__global__ __launch_bounds__(256) void prep(const float* __restrict__ fcinW,
                                            const float* __restrict__ Wih,
                                            const float* __restrict__ Whh,
                                            const float* __restrict__ bih,
                                            const float* __restrict__ bhh,
                                            const float* __restrict__ fcoutW,
                                            h16* __restrict__ wsh,
                                            float* __restrict__ wbias) {
  int idx = blockIdx.x * 256 + threadIdx.x;
  if (idx < 65536) {                          // fc_in_W [128][4096], Kd8=512
    int r = idx >> 9, k8 = idx & 511;
    const float* src = fcinW + r * 4096 + k8 * 8;
    h8 v = cvt8(*(const float4*)src, *(const float4*)(src + 4));
    *(h8*)(wsh + OFF_FCIN + (((r >> 4) * 512 + k8) * 128 + (r & 15) * 8)) = v;
  } else if (idx < 229376) {                  // Wih/Whh [10][512][128], Kd8=16, pre-scaled
    int rel = idx - 65536;
    int l = rel >> 14, rr = rel & 16383;
    int ssel = rr >> 13, rk8 = rr & 8191;
    int r = rk8 >> 4, k8 = rk8 & 15;
    float sc = ((r >> 7) == 2) ? (-2.f * L2E) : (-L2E);
    const float* src = (ssel ? Whh : Wih) + l * 65536 + r * 128 + k8 * 8;
    h8 v = cvt8s(*(const float4*)src, *(const float4*)(src + 4), sc);
    *(h8*)(wsh + OFF_W + (l * 2 + ssel) * 65536 +
           (((r >> 4) * 16 + k8) * 128 + (r & 15) * 8)) = v;
  } else if (idx < 230656) {                  // fc_out_W padded to [80][128]
    int rel = idx - 229376;
    int r = rel >> 4, k8 = rel & 15;
    h8 v;
    if (r < 75) {
      const float* src = fcoutW + r * 128 + k8 * 8;
      v = cvt8(*(const float4*)src, *(const float4*)(src + 4));
    } else {
      for (int j = 0; j < 8; ++j) v[j] = (h16)0.f;
    }
    *(h8*)(wsh + OFF_FCOUT + (((r >> 4) * 16 + k8) * 128 + (r & 15) * 8)) = v;
  } else if (idx < 235776) {
    int rel = idx - 230656;
    int col = rel & 511;
    float sc = ((col >> 7) == 2) ? (-2.f * L2E) : (-L2E);
    wbias[rel] = (bih[rel] + bhh[rel]) * sc;
  }
}

// ---------------- fc_in GEMM: enc = relu(A @ W^T + b), fp16 out ----------------
// K-split: each of the 4 waves handles a 1024-wide K-chunk of the SAME 16 rows
// (A read exactly once per block), covering all 128 output cols (8 col-tiles).
// Partial sums reduced through LDS; bias+ReLU fused in the reduction.
__global__ __launch_bounds__(256) void kin(const float* __restrict__ A,
                                           const float* __restrict__ bvec,
                                           h16* __restrict__ wsh) {
  __shared__ float red[4][16][129];   // 33 KB
  const h16* Wp = wsh + OFF_FCIN;
  h16* ench = wsh + OFF_ENC;
  int tid = threadIdx.x;
  int w = tid >> 6, lane = tid & 63, s = lane & 15, q = lane >> 4;
  int m0 = blockIdx.x * 16;
  f4 acc[8];
#pragma unroll
  for (int ct = 0; ct < 8; ++ct) acc[ct] = splat4(0.f);
  const float* arow = A + (size_t)(m0 + s) * NENC + w * 1024;
  const h16* wpk = Wp + ((size_t)(w * 128 + q)) * 128 + s * 8;
#pragma unroll 4
  for (int kb = 0; kb < 32; ++kb) {
    int k0 = kb * 32 + q * 8;
    float4 x0 = *(const float4*)(arow + k0);
    float4 x1 = *(const float4*)(arow + k0 + 4);
    h8 af = cvt8(x0, x1);
#pragma unroll
    for (int ct = 0; ct < 8; ++ct) {
      h8 b = *(const h8*)(wpk + ((size_t)ct * 512 + kb * 4) * 128);
      acc[ct] = __builtin_amdgcn_mfma_f32_16x16x32_f16(af, b, acc[ct], 0, 0, 0);
    }
  }
#pragma unroll
  for (int ct = 0; ct < 8; ++ct)
#pragma unroll
    for (int r = 0; r < 4; ++r)
      red[w][q * 4 + r][ct * 16 + s] = acc[ct][r];
  __syncthreads();
#pragma unroll
  for (int i = 0; i < 8; ++i) {
    int idx = tid + i * 256;
    int row = idx >> 7, col = idx & 127;
    float v = red[0][row][col] + red[1][row][col] + red[2][row][col] + red[3][row][col]
            + bvec[col];
    v = v > 0.f ? v : 0.f;
    ench[(size_t)(m0 + row) * NH + col] = (h16)v;
  }
}

// ---------------- kin2: GX0 = enc @ Wih0^T + b0 (t-invariant layer-0 x-GEMM) ----
__global__ __launch_bounds__(256) void kin2(h16* __restrict__ wsh,
                                            const float* __restrict__ wbias) {
  int tid = threadIdx.x;
  int w2 = tid >> 6, lane = tid & 63, s = lane & 15, q = lane >> 4;
  int bid = blockIdx.x;
  int lb = bid >> 3, mt = (bid >> 2) & 1, cg = bid & 3;
  const h16* ench = wsh + OFF_ENC;
  const h16* wih0 = wsh + OFF_W;
  h16* gx0 = wsh + OFF_GX0;
  const h16* arow = ench + (size_t)(lb * 32 + mt * 16 + s) * NH;
  h8 ax[4];
#pragma unroll
  for (int kt = 0; kt < 4; ++kt) ax[kt] = *(const h8*)(arow + kt * 32 + q * 8);
#pragma unroll
  for (int ti = 0; ti < 2; ++ti) {
    int W = w2 * 2 + ti;
    int rb = cg * 8 + W;
    f4 acc = splat4(wbias[cg * 128 + W * 16 + s]);
#pragma unroll
    for (int kt = 0; kt < 4; ++kt) {
      h8 b = *(const h8*)(wih0 + (rb * 16 + kt * 4 + q) * 128 + s * 8);
      acc = __builtin_amdgcn_mfma_f32_16x16x32_f16(ax[kt], b, acc, 0, 0, 0);
    }
    h4 st; st[0] = (h16)acc[0]; st[1] = (h16)acc[1]; st[2] = (h16)acc[2]; st[3] = (h16)acc[3];
    *(h4*)(gx0 + ((((size_t)lb * 8 + W) * 8 + cg * 2 + mt) * 64 + lane) * 4) = st;
  }
}

// ---------------- persistent LSTM + output head ----------------
// grid 256 = 1 WG/CU, block 512 = 8 waves (2/SIMD), 32 batch rows/WG.
// Round-2 schedule (measured best): per (l,t) one barrier; h-GEMM chains into
// acc (which entered holding bias + x(t) from the in-iteration x-GEMM of the
// previous step); cell; x-GEMM(t+1) reads LDS in-iteration next to the MFMA
// stream (round-3's pre-barrier prefetch regressed: lgkmcnt(0) drains at the
// barrier anyway, serializing the reads at the iteration tail).
__global__ __launch_bounds__(512, 2) void lstm(h16* __restrict__ wsh,
                                               const float* __restrict__ wbias,
                                               const float* __restrict__ fcoutb,
                                               float* __restrict__ out) {
  __shared__ h16 ring[32][13][PAD];   // 113152 B
  __shared__ float probst[32 * 26];
  int tid = threadIdx.x;
  int w = tid >> 6, lane = tid & 63, s = lane & 15, q = lane >> 4;
  int brow = blockIdx.x * 32;
  h8 wx[4][4], wh[4][4];
  f4 bbv[4];
  f4 c[2];
  h16* rd0 = &ring[s][0][q * 8];
  h16* rd1 = &ring[16 + s][0][q * 8];
  h16* wr0 = &ring[q * 4][0][w * 16 + s];
  h16* wr1 = &ring[16 + q * 4][0][w * 16 + s];
#define RSTRIDE (13 * PAD)   // row stride in halfs (3536 B)

  // ---------- layer 0: acc chains from register-resident GX0 ----------
  {
    const h16* whh = wsh + OFF_W + 65536;
#pragma unroll
    for (int g = 0; g < 4; ++g)
#pragma unroll
      for (int kt = 0; kt < 4; ++kt)
        wh[g][kt] = *(const h8*)(whh + (((g * 8 + w) * 16 + kt * 4 + q) * 128) + s * 8);
    f4 gx[4][2];
    const h16* gxp = wsh + OFF_GX0 + ((size_t)blockIdx.x * 8 + w) * 8 * 256 + (size_t)lane * 4;
#pragma unroll
    for (int g = 0; g < 4; ++g)
#pragma unroll
      for (int mt = 0; mt < 2; ++mt) {
        h4 v = *(const h4*)(gxp + (g * 2 + mt) * 256);
        f4 a; a[0] = (float)v[0]; a[1] = (float)v[1]; a[2] = (float)v[2]; a[3] = (float)v[3];
        gx[g][mt] = a;
      }
    c[0] = splat4(0.f); c[1] = splat4(0.f);
    // t = 0: cell directly on gx, write to slot 11
    {
      h16* q0 = wr0 + 11 * PAD;
      h16* q1 = wr1 + 11 * PAD;
      h4 h0 = cell4(gx[0][0], gx[1][0], gx[2][0], gx[3][0], c[0]);
      h4 h1 = cell4(gx[0][1], gx[1][1], gx[2][1], gx[3][1], c[1]);
#pragma unroll
      for (int r = 0; r < 4; ++r) { q0[r * RSTRIDE] = h0[r]; q1[r * RSTRIDE] = h1[r]; }
    }
    int rw = 12;
    for (int t = 1; t < NT; ++t) {
      __syncthreads();
      int rh = rw - 1; if (rh < 0) rh += 13;
      f4 acc[4][2];
      const h16* p0 = rd0 + rh * PAD;
      const h16* p1 = rd1 + rh * PAD;
#pragma unroll
      for (int mt = 0; mt < 2; ++mt) {
        const h16* pp = mt ? p1 : p0;
        h8 ah[4];
#pragma unroll
        for (int kt = 0; kt < 4; ++kt) ah[kt] = *(const h8*)(pp + kt * 32);
#pragma unroll
        for (int g = 0; g < 4; ++g) {
          acc[g][mt] = __builtin_amdgcn_mfma_f32_16x16x32_f16(ah[0], wh[g][0], gx[g][mt], 0, 0, 0);
#pragma unroll
          for (int kt = 1; kt < 4; ++kt)
            acc[g][mt] = __builtin_amdgcn_mfma_f32_16x16x32_f16(ah[kt], wh[g][kt], acc[g][mt], 0, 0, 0);
        }
      }
      h16* q0 = wr0 + rw * PAD;
      h16* q1 = wr1 + rw * PAD;
      h4 h0 = cell4(acc[0][0], acc[1][0], acc[2][0], acc[3][0], c[0]);
      h4 h1 = cell4(acc[0][1], acc[1][1], acc[2][1], acc[3][1], c[1]);
#pragma unroll
      for (int r = 0; r < 4; ++r) { q0[r * RSTRIDE] = h0[r]; q1[r * RSTRIDE] = h1[r]; }
      ++rw; if (rw >= 13) rw = 0;
    }
  }
  // ---------- layers 1..9 (round-2 schedule, bias-in-C) ----------
  for (int l = 1; l < NL; ++l) {
    const h16* wih = wsh + OFF_W + (size_t)(l * 2) * 65536;
    const h16* whh = wih + 65536;
#pragma unroll
    for (int g = 0; g < 4; ++g) {
#pragma unroll
      for (int kt = 0; kt < 4; ++kt) {
        int off = (((g * 8 + w) * 16 + kt * 4 + q) * 128) + s * 8;
        wx[g][kt] = *(const h8*)(wih + off);
        wh[g][kt] = *(const h8*)(whh + off);
      }
      bbv[g] = splat4(wbias[l * 512 + g * 128 + w * 16 + s]);
    }
    c[0] = splat4(0.f); c[1] = splat4(0.f);
    int rw = 11 - l;                 // rw(t=0) in [2,10]
    f4 acc[4][2];
    // hoisted x-GEMM(0): slot rw+1 was written 12 barriers ago, race-free.
    {
      const h16* p0 = rd0 + (rw + 1) * PAD;
      const h16* p1 = rd1 + (rw + 1) * PAD;
#pragma unroll
      for (int mt = 0; mt < 2; ++mt) {
        const h16* pp = mt ? p1 : p0;
        h8 ax[4];
#pragma unroll
        for (int kt = 0; kt < 4; ++kt) ax[kt] = *(const h8*)(pp + kt * 32);
#pragma unroll
        for (int g = 0; g < 4; ++g) {
          acc[g][mt] = __builtin_amdgcn_mfma_f32_16x16x32_f16(ax[0], wx[g][0], bbv[g], 0, 0, 0);
#pragma unroll
          for (int kt = 1; kt < 4; ++kt)
            acc[g][mt] = __builtin_amdgcn_mfma_f32_16x16x32_f16(ax[kt], wx[g][kt], acc[g][mt], 0, 0, 0);
        }
      }
    }
    for (int t = 0; t < NT; ++t) {
      __syncthreads();
      if (t > 0) {                   // h-GEMM chains into acc (holds bias + x(t))
        int rh = rw - 1; if (rh < 0) rh += 13;
        const h16* p0 = rd0 + rh * PAD;
        const h16* p1 = rd1 + rh * PAD;
#pragma unroll
        for (int mt = 0; mt < 2; ++mt) {
          const h16* pp = mt ? p1 : p0;
          h8 ah[4];
#pragma unroll
          for (int kt = 0; kt < 4; ++kt) ah[kt] = *(const h8*)(pp + kt * 32);
#pragma unroll
          for (int g = 0; g < 4; ++g)
#pragma unroll
            for (int kt = 0; kt < 4; ++kt)
              acc[g][mt] = __builtin_amdgcn_mfma_f32_16x16x32_f16(ah[kt], wh[g][kt], acc[g][mt], 0, 0, 0);
        }
      }
      // cell(t)
      h4 h0 = cell4(acc[0][0], acc[1][0], acc[2][0], acc[3][0], c[0]);
      h4 h1 = cell4(acc[0][1], acc[1][1], acc[2][1], acc[3][1], c[1]);
      if (t < 11) {                  // x-GEMM(t+1) from LDS (in-iteration), C = bias
        int rx = rw + 2; if (rx >= 13) rx -= 13;
        const h16* p0 = rd0 + rx * PAD;
        const h16* p1 = rd1 + rx * PAD;
#pragma unroll
        for (int mt = 0; mt < 2; ++mt) {
          const h16* pp = mt ? p1 : p0;
          h8 ax[4];
#pragma unroll
          for (int kt = 0; kt < 4; ++kt) ax[kt] = *(const h8*)(pp + kt * 32);
#pragma unroll
          for (int g = 0; g < 4; ++g) {
            acc[g][mt] = __builtin_amdgcn_mfma_f32_16x16x32_f16(ax[0], wx[g][0], bbv[g], 0, 0, 0);
#pragma unroll
            for (int kt = 1; kt < 4; ++kt)
              acc[g][mt] = __builtin_amdgcn_mfma_f32_16x16x32_f16(ax[kt], wx[g][kt], acc[g][mt], 0, 0, 0);
          }
        }
      }
      h16* q0 = wr0 + rw * PAD;
      h16* q1 = wr1 + rw * PAD;
#pragma unroll
      for (int r = 0; r < 4; ++r) { q0[r * RSTRIDE] = h0[r]; q1[r * RSTRIDE] = h1[r]; }
      ++rw; if (rw >= 13) rw = 0;
    }
  }
  // ---- output head: layer-9 h(t) lives in ring slot (t+2)%13 ----
  __syncthreads();
  h8 wo[5][4];
  float bo[5];
  const h16* fco = wsh + OFF_FCOUT;
#pragma unroll
  for (int nt = 0; nt < 5; ++nt) {
#pragma unroll
    for (int kt = 0; kt < 4; ++kt)
      wo[nt][kt] = *(const h8*)(fco + (nt * 16 + kt * 4 + q) * 128 + s * 8);
    int col = nt * 16 + s;
    bo[nt] = (col < 75) ? fcoutb[col] : 0.f;
  }
  int tcount = (w < 4) ? 2 : 1;
  for (int ti = 0; ti < tcount; ++ti) {
    int t = w + ti * 8;
    int sl = t + 2; if (sl >= 13) sl -= 13;
#pragma unroll
    for (int mt = 0; mt < 2; ++mt) {
      const h16* pp = (mt ? rd1 : rd0) + sl * PAD;
      h8 ax[4];
#pragma unroll
      for (int kt = 0; kt < 4; ++kt) ax[kt] = *(const h8*)(pp + kt * 32);
#pragma unroll
      for (int nt = 0; nt < 5; ++nt) {
        f4 a = splat4(bo[nt]);
#pragma unroll
        for (int kt = 0; kt < 4; ++kt)
          a = __builtin_amdgcn_mfma_f32_16x16x32_f16(ax[kt], wo[nt][kt], a, 0, 0, 0);
        int col = nt * 16 + s;
#pragma unroll
        for (int r = 0; r < 4; ++r) {
          int row = mt * 16 + q * 4 + r;
          int b = brow + row;
          float v = a[r];
          if (col < 50)
            out[(size_t)b * 600 + (col >> 1) * 24 + t * 2 + (col & 1)] = v;
          if (t == 11 && col >= 50 && col < 75)
            probst[row * 26 + (col - 50)] = v;
        }
      }
    }
  }
  __syncthreads();
  if (tid < 32) {
    float vals[25];
    float m = -1e30f;
#pragma unroll
    for (int j = 0; j < 25; ++j) { vals[j] = probst[tid * 26 + j]; m = vals[j] > m ? vals[j] : m; }
    float sum = 0.f;
#pragma unroll
    for (int j = 0; j < 25; ++j) {
      float e = __builtin_amdgcn_exp2f((vals[j] - m) * L2E);
      vals[j] = e; sum += e;
    }
    float rs = 1.0f / sum;
    size_t pb = (size_t)4915200 + (size_t)(brow + tid) * 25;
#pragma unroll
    for (int j = 0; j < 25; ++j) out[pb + j] = vals[j] * rs;
  }
}

extern "C" void kernel_launch(void* const* d_in, const int* in_sizes, int n_in,
                              void* d_out, int out_size, void* d_ws, size_t ws_size,
                              hipStream_t stream) {
  const float* backbone = (const float*)d_in[0];
  const float* fcinW    = (const float*)d_in[1];
  const float* fcinb    = (const float*)d_in[2];
  const float* Wih      = (const float*)d_in[3];
  const float* Whh      = (const float*)d_in[4];
  const float* bih      = (const float*)d_in[5];
  const float* bhh      = (const float*)d_in[6];
  const float* fcoutW   = (const float*)d_in[7];
  const float* fcoutb   = (const float*)d_in[8];
  h16* wsh = (h16*)d_ws;
  float* wbias = (float*)((char*)d_ws + BYTE_BIAS);

  prep<<<922, 256, 0, stream>>>(fcinW, Wih, Whh, bih, bhh, fcoutW, wsh, wbias);
  kin<<<512, 256, 0, stream>>>(backbone, fcinb, wsh);
  kin2<<<2048, 256, 0, stream>>>(wsh, wbias);
  lstm<<<256, 512, 0, stream>>>(wsh, wbias, fcoutb, (float*)d_out);
}